// Round 1
// baseline (1100.840 us; speedup 1.0000x reference)
//
#include <hip/hip_runtime.h>

#define NA 50000
#define NT 25000
#define EAA 800000
#define EAT 400000
#define ETA 400000

// ---- workspace layout (float offsets) ----
#define OFF_CAA 0            // 50000: homo agent coef  rsqrt(indeg+1)
#define OFF_ATS 50048        // 50000: at-relation src coef (over NA)
#define OFF_ATD 100096       // 25000: at-relation dst coef (over NT)
#define OFF_TAS 125120       // 25000: ta-relation src coef (over NT)
#define OFF_TAD 150144       // 50000: ta-relation dst coef (over NA)
#define COEF_FLOATS 200192
#define OFF_U   200192       // U_aa[128] | U_ta[+128] | U_at[+256] | v[+384..388]
#define OFF_HA  200704       // 3,200,000: h_a [NA x 64]
#define OFF_HT  3400704      // 1,600,000: h_t [NT x 64]
#define OFF_AGG 5000704      // conv1 aggs: aa[1.6M] | ta[+1.6M] | at[+3.2M]
#define AGG_FLOATS 4000000
// after conv1, AGG region is reused:
#define OFF_P   OFF_AGG             // p_a [NA x 2]
#define OFF_Q   (OFF_AGG + 100096)  // q_a [NA x 2]
#define OFF_R   (OFF_AGG + 200192)  // r_t [NT x 2]

// ---------- degree counting ----------
__global__ void deg1_kernel(const int* __restrict__ idx, float* __restrict__ cnt, int E) {
    int t = blockIdx.x * blockDim.x + threadIdx.x;
    if (t < E) atomicAdd(&cnt[idx[t]], 1.0f);
}

__global__ void deg2_kernel(const int* __restrict__ s, const int* __restrict__ d,
                            float* __restrict__ cs, float* __restrict__ cd, int E) {
    int t = blockIdx.x * blockDim.x + threadIdx.x;
    if (t < E) {
        atomicAdd(&cs[s[t]], 1.0f);
        atomicAdd(&cd[d[t]], 1.0f);
    }
}

// counts -> normalization coefficients, in place
__global__ void coef_kernel(float* __restrict__ ws) {
    int t = blockIdx.x * blockDim.x + threadIdx.x;
    if (t < 50000) {                     // homo: rsqrt(indeg + 1)
        float* p = ws + OFF_CAA + t;
        *p = rsqrtf(*p + 1.0f);
    } else if (t < 100000) {             // bi: deg>0 ? rsqrt(deg) : 0
        float* p = ws + OFF_ATS + (t - 50000);
        float c = *p; *p = (c > 0.f) ? rsqrtf(c) : 0.f;
    } else if (t < 125000) {
        float* p = ws + OFF_ATD + (t - 100000);
        float c = *p; *p = (c > 0.f) ? rsqrtf(c) : 0.f;
    } else if (t < 150000) {
        float* p = ws + OFF_TAS + (t - 125000);
        float c = *p; *p = (c > 0.f) ? rsqrtf(c) : 0.f;
    } else if (t < 200000) {
        float* p = ws + OFF_TAD + (t - 150000);
        float c = *p; *p = (c > 0.f) ? rsqrtf(c) : 0.f;
    }
}

// ---------- conv1: aggregate 32-dim inputs (atomic scatter) ----------
// 8 threads per edge, each handles a float4 slice of the 32-dim row.
__global__ void scatter32_kernel(const float* __restrict__ x, const int* __restrict__ src,
                                 const int* __restrict__ dst, const float* __restrict__ cs,
                                 const float* __restrict__ cd, float* __restrict__ agg, int E) {
    int tid = blockIdx.x * blockDim.x + threadIdx.x;
    if (tid >= E * 8) return;
    int e = tid >> 3, k = tid & 7;
    int s = src[e], d = dst[e];
    float w = cs[s] * cd[d];
    float4 xv = *(const float4*)(x + (size_t)s * 32 + k * 4);
    float* out = agg + (size_t)d * 32 + k * 4;
    atomicAdd(out + 0, xv.x * w);
    atomicAdd(out + 1, xv.y * w);
    atomicAdd(out + 2, xv.z * w);
    atomicAdd(out + 3, xv.w * w);
}

// ---------- conv1 dense transform for agents: h_a = relu((agg_aa + x*c^2)@W1_aa + agg_ta@W1_ta + b1_aa + b1_ta) ----------
__global__ void __launch_bounds__(256)
conv1_agents_kernel(const float* __restrict__ x, const float* __restrict__ agg_aa,
                    const float* __restrict__ agg_ta, const float* __restrict__ c_aa,
                    const float* __restrict__ W_aa, const float* __restrict__ b_aa,
                    const float* __restrict__ W_ta, const float* __restrict__ b_ta,
                    float* __restrict__ h, int n) {
    __shared__ float sWa[32 * 64];
    __shared__ float sWt[32 * 64];
    for (int i = threadIdx.x; i < 2048; i += blockDim.x) {
        sWa[i] = W_aa[i];
        sWt[i] = W_ta[i];
    }
    __syncthreads();
    int lane = threadIdx.x & 63;
    int wave = threadIdx.x >> 6;
    int wpb = blockDim.x >> 6;
    float bias = b_aa[lane] + b_ta[lane];
    for (int i = blockIdx.x * wpb + wave; i < n; i += gridDim.x * wpb) {
        float c = c_aa[i];
        float c2 = c * c;
        const float* xa = x + (size_t)i * 32;
        const float* ga = agg_aa + (size_t)i * 32;
        const float* gt = agg_ta + (size_t)i * 32;
        float acc = bias;
#pragma unroll
        for (int k = 0; k < 32; ++k) {
            float a1 = ga[k] + xa[k] * c2;
            acc = fmaf(a1, sWa[k * 64 + lane], acc);
            acc = fmaf(gt[k], sWt[k * 64 + lane], acc);
        }
        h[(size_t)i * 64 + lane] = fmaxf(acc, 0.f);
    }
}

// ---------- conv1 dense transform for targets: h_t = relu(agg_at@W1_at + b1_at) ----------
__global__ void __launch_bounds__(256)
conv1_targets_kernel(const float* __restrict__ agg_at, const float* __restrict__ W_at,
                     const float* __restrict__ b_at, float* __restrict__ h, int n) {
    __shared__ float sW[32 * 64];
    for (int i = threadIdx.x; i < 2048; i += blockDim.x) sW[i] = W_at[i];
    __syncthreads();
    int lane = threadIdx.x & 63;
    int wave = threadIdx.x >> 6;
    int wpb = blockDim.x >> 6;
    float bias = b_at[lane];
    for (int i = blockIdx.x * wpb + wave; i < n; i += gridDim.x * wpb) {
        const float* ga = agg_at + (size_t)i * 32;
        float acc = bias;
#pragma unroll
        for (int k = 0; k < 32; ++k) acc = fmaf(ga[k], sW[k * 64 + lane], acc);
        h[(size_t)i * 64 + lane] = fmaxf(acc, 0.f);
    }
}

// ---------- fuse conv2 weights with output projection: U_* = W2_* @ Wp_* (64x2), v = fused biases ----------
__global__ void fuse_kernel(const float* __restrict__ W2_aa, const float* __restrict__ W2_ta,
                            const float* __restrict__ W2_at, const float* __restrict__ b2_aa,
                            const float* __restrict__ b2_ta, const float* __restrict__ b2_at,
                            const float* __restrict__ Wp_a, const float* __restrict__ bp_a,
                            const float* __restrict__ Wp_t, const float* __restrict__ bp_t,
                            float* __restrict__ U) {
    int t = threadIdx.x;  // 512-thread single block
    float* U_aa = U;
    float* U_ta = U + 128;
    float* U_at = U + 256;
    float* v = U + 384;
    if (t < 128) {
        int k = t >> 1, j = t & 1;
        float a = 0.f;
        for (int f = 0; f < 64; ++f) a = fmaf(W2_aa[k * 64 + f], Wp_a[f * 2 + j], a);
        U_aa[k * 2 + j] = a;
    } else if (t < 256) {
        int u = t - 128; int k = u >> 1, j = u & 1;
        float a = 0.f;
        for (int f = 0; f < 64; ++f) a = fmaf(W2_ta[k * 64 + f], Wp_a[f * 2 + j], a);
        U_ta[k * 2 + j] = a;
    } else if (t < 384) {
        int u = t - 256; int k = u >> 1, j = u & 1;
        float a = 0.f;
        for (int f = 0; f < 64; ++f) a = fmaf(W2_at[k * 64 + f], Wp_t[f * 2 + j], a);
        U_at[k * 2 + j] = a;
    } else if (t < 386) {
        int j = t - 384;
        float a = bp_a[j];
        for (int f = 0; f < 64; ++f) a = fmaf(b2_aa[f] + b2_ta[f], Wp_a[f * 2 + j], a);
        v[j] = a;
    } else if (t < 388) {
        int j = t - 386;
        float a = bp_t[j];
        for (int f = 0; f < 64; ++f) a = fmaf(b2_at[f], Wp_t[f * 2 + j], a);
        v[2 + j] = a;
    }
}

// ---------- transform h to 2-dim pre-scatter values: p = h@U_aa, q = h@U_at (agents) ----------
__global__ void pq_agents_kernel(const float* __restrict__ h, const float* __restrict__ U,
                                 float* __restrict__ p, float* __restrict__ q, int n) {
    int t = blockIdx.x * blockDim.x + threadIdx.x;
    if (t >= n * 4) return;
    int i = t >> 2, which = t & 3;
    const float* Um = (which < 2) ? U : (U + 256);  // U_aa or U_at
    int j = which & 1;
    const float* hr = h + (size_t)i * 64;
    float acc = 0.f;
#pragma unroll
    for (int k = 0; k < 64; ++k) acc = fmaf(hr[k], Um[k * 2 + j], acc);
    if (which < 2) p[i * 2 + j] = acc;
    else           q[i * 2 + j] = acc;
}

__global__ void r_targets_kernel(const float* __restrict__ h, const float* __restrict__ U,
                                 float* __restrict__ r, int n) {
    int t = blockIdx.x * blockDim.x + threadIdx.x;
    if (t >= n * 2) return;
    int i = t >> 1, j = t & 1;
    const float* Um = U + 128;  // U_ta
    const float* hr = h + (size_t)i * 64;
    float acc = 0.f;
#pragma unroll
    for (int k = 0; k < 64; ++k) acc = fmaf(hr[k], Um[k * 2 + j], acc);
    r[i * 2 + j] = acc;
}

// ---------- initialize output with fused bias + homo self-loop term ----------
__global__ void init_out_kernel(float* __restrict__ out, const float* __restrict__ p,
                                const float* __restrict__ c_aa, const float* __restrict__ U) {
    int t = blockIdx.x * blockDim.x + threadIdx.x;
    const float* v = U + 384;
    const int na2 = NA * 2;
    if (t < na2) {
        int i = t >> 1, j = t & 1;
        float c = c_aa[i];
        out[t] = v[j] + p[t] * c * c;
    } else if (t < na2 + NT * 2) {
        out[t] = v[2 + (t & 1)];
    }
}

// ---------- conv2 edge scatter: only 2 floats per edge ----------
__global__ void scatter2_kernel(const float* __restrict__ val, const int* __restrict__ src,
                                const int* __restrict__ dst, const float* __restrict__ cs,
                                const float* __restrict__ cd, float* __restrict__ out, int E) {
    int t = blockIdx.x * blockDim.x + threadIdx.x;
    if (t >= E * 2) return;
    int e = t >> 1, j = t & 1;
    int s = src[e], d = dst[e];
    float w = cs[s] * cd[d];
    atomicAdd(out + d * 2 + j, val[s * 2 + j] * w);
}

extern "C" void kernel_launch(void* const* d_in, const int* in_sizes, int n_in,
                              void* d_out, int out_size, void* d_ws, size_t ws_size,
                              hipStream_t stream) {
    const float* x_a   = (const float*)d_in[1];
    const float* x_t   = (const float*)d_in[2];
    const int* src_aa  = (const int*)d_in[3];
    const int* dst_aa  = (const int*)d_in[4];
    const int* src_at  = (const int*)d_in[5];
    const int* dst_at  = (const int*)d_in[6];
    const int* src_ta  = (const int*)d_in[7];
    const int* dst_ta  = (const int*)d_in[8];
    const float* W1_aa = (const float*)d_in[9];
    const float* b1_aa = (const float*)d_in[10];
    const float* W1_at = (const float*)d_in[11];
    const float* b1_at = (const float*)d_in[12];
    const float* W1_ta = (const float*)d_in[13];
    const float* b1_ta = (const float*)d_in[14];
    const float* W2_aa = (const float*)d_in[15];
    const float* b2_aa = (const float*)d_in[16];
    const float* W2_at = (const float*)d_in[17];
    const float* b2_at = (const float*)d_in[18];
    const float* W2_ta = (const float*)d_in[19];
    const float* b2_ta = (const float*)d_in[20];
    const float* Wp_a  = (const float*)d_in[21];
    const float* bp_a  = (const float*)d_in[22];
    const float* Wp_t  = (const float*)d_in[23];
    const float* bp_t  = (const float*)d_in[24];

    float* ws  = (float*)d_ws;
    float* out = (float*)d_out;

    const int B = 256;
    auto blk = [](int n) { return (n + 255) / 256; };

    // zero degree/coef region and conv1 aggregation region
    hipMemsetAsync(ws, 0, (size_t)COEF_FLOATS * 4, stream);
    hipMemsetAsync(ws + OFF_AGG, 0, (size_t)AGG_FLOATS * 4, stream);

    // degrees
    deg1_kernel<<<blk(EAA), B, 0, stream>>>(dst_aa, ws + OFF_CAA, EAA);
    deg2_kernel<<<blk(EAT), B, 0, stream>>>(src_at, dst_at, ws + OFF_ATS, ws + OFF_ATD, EAT);
    deg2_kernel<<<blk(ETA), B, 0, stream>>>(src_ta, dst_ta, ws + OFF_TAS, ws + OFF_TAD, ETA);
    coef_kernel<<<blk(200000), B, 0, stream>>>(ws);

    // conv1 aggregation (32-dim input features, aggregate-before-transform)
    scatter32_kernel<<<blk(EAA * 8), B, 0, stream>>>(x_a, src_aa, dst_aa, ws + OFF_CAA, ws + OFF_CAA, ws + OFF_AGG, EAA);
    scatter32_kernel<<<blk(ETA * 8), B, 0, stream>>>(x_t, src_ta, dst_ta, ws + OFF_TAS, ws + OFF_TAD, ws + OFF_AGG + 1600000, ETA);
    scatter32_kernel<<<blk(EAT * 8), B, 0, stream>>>(x_a, src_at, dst_at, ws + OFF_ATS, ws + OFF_ATD, ws + OFF_AGG + 3200000, EAT);

    // conv1 dense transforms + relu
    conv1_agents_kernel<<<blk(NA * 64), B, 0, stream>>>(
        x_a, ws + OFF_AGG, ws + OFF_AGG + 1600000, ws + OFF_CAA,
        W1_aa, b1_aa, W1_ta, b1_ta, ws + OFF_HA, NA);
    conv1_targets_kernel<<<blk(NT * 64), B, 0, stream>>>(
        ws + OFF_AGG + 3200000, W1_at, b1_at, ws + OFF_HT, NT);

    // fuse conv2 weights with output projection (64x2 each)
    fuse_kernel<<<1, 512, 0, stream>>>(W2_aa, W2_ta, W2_at, b2_aa, b2_ta, b2_at,
                                       Wp_a, bp_a, Wp_t, bp_t, ws + OFF_U);

    // transform-first for conv2+proj: 2 floats per node per relation
    pq_agents_kernel<<<blk(NA * 4), B, 0, stream>>>(ws + OFF_HA, ws + OFF_U, ws + OFF_P, ws + OFF_Q, NA);
    r_targets_kernel<<<blk(NT * 2), B, 0, stream>>>(ws + OFF_HT, ws + OFF_U, ws + OFF_R, NT);

    // init output with fused biases + homo self-loop, then scatter 2 floats/edge
    init_out_kernel<<<blk((NA + NT) * 2), B, 0, stream>>>(out, ws + OFF_P, ws + OFF_CAA, ws + OFF_U);
    scatter2_kernel<<<blk(EAA * 2), B, 0, stream>>>(ws + OFF_P, src_aa, dst_aa, ws + OFF_CAA, ws + OFF_CAA, out, EAA);
    scatter2_kernel<<<blk(ETA * 2), B, 0, stream>>>(ws + OFF_R, src_ta, dst_ta, ws + OFF_TAS, ws + OFF_TAD, out, ETA);
    scatter2_kernel<<<blk(EAT * 2), B, 0, stream>>>(ws + OFF_Q, src_at, dst_at, ws + OFF_ATS, ws + OFF_ATD, out + NA * 2, EAT);
}

// Round 2
// 483.637 us; speedup vs baseline: 2.2762x; 2.2762x over previous
//
#include <hip/hip_runtime.h>

#define NA 50000
#define NT 25000
#define EAA 800000
#define EAT 400000
#define ETA 400000
#define NSEG 125000          // NA + NA + NT rows: [aa | ta | at]
#define TOTAL_E 1600000

// ---- workspace layout (4-byte element offsets) ----
#define O_DEGC    0          // int[125008]: concat degrees  aa-dst[NA] | ta-dst[NA] | at-dst[NT]
#define O_ATSRC   125008     // int[50000]: at-relation src out-degree (over NA)
#define O_TASRC   175008     // int[25000]: ta-relation src out-degree (over NT)
#define O_ZEND    200032     // memset 0 .. here
#define O_RO      200032     // int[125008]: CSR row offsets (global into edge buffer)
#define O_CUR     325040     // int[125000]: fill cursors
#define O_BSUM    450040     // int[512]: scan block sums
#define O_CAA     450552     // float[50000]: rsqrt(indeg_aa+1)
#define O_CTAD    500552     // float[50000]: ta dst coef (over NA)
#define O_CATD    550552     // float[25000]: at dst coef (over NT)
#define O_CATS    575552     // float[50000]: at src coef (over NA)
#define O_CTAS    625552     // float[25000]: ta src coef (over NT)
#define O_U       650552     // float[512]: U_aa[128] | U_ta[128] | U_at[128] | v[4]
#define O_P       651064     // float[100000]: p = h_a @ U_aa
#define O_Q       751064     // float[100000]: q = h_a @ U_at
#define O_R       851064     // float[50000]:  r = h_t @ U_ta
#define O_CSRS    901064     // int[1600000]: CSR src indices
#define O_CSRW    2501064    // float[1600000]: CSR edge weight = c_src[src]
// total 4,101,064 elems = 16.4 MB

// ---------- degree counting (int) ----------
__global__ void deg1_kernel(const int* __restrict__ dst, int* __restrict__ cnt, int E) {
    int t = blockIdx.x * blockDim.x + threadIdx.x;
    if (t < E) atomicAdd(&cnt[dst[t]], 1);
}
__global__ void deg2_kernel(const int* __restrict__ src, const int* __restrict__ dst,
                            int* __restrict__ cs, int* __restrict__ cd, int E) {
    int t = blockIdx.x * blockDim.x + threadIdx.x;
    if (t < E) {
        atomicAdd(&cd[dst[t]], 1);
        atomicAdd(&cs[src[t]], 1);
    }
}

// ---------- degrees -> normalization coefficients ----------
__global__ void coef_kernel(const int* __restrict__ wi, float* __restrict__ wf) {
    int t = blockIdx.x * blockDim.x + threadIdx.x;
    if (t < 50000) {
        wf[O_CAA + t] = rsqrtf((float)wi[O_DEGC + t] + 1.0f);
    } else if (t < 100000) {
        int i = t - 50000; int d = wi[O_DEGC + NA + i];
        wf[O_CTAD + i] = d > 0 ? rsqrtf((float)d) : 0.0f;
    } else if (t < 125000) {
        int i = t - 100000; int d = wi[O_DEGC + 2 * NA + i];
        wf[O_CATD + i] = d > 0 ? rsqrtf((float)d) : 0.0f;
    } else if (t < 175000) {
        int i = t - 125000; int d = wi[O_ATSRC + i];
        wf[O_CATS + i] = d > 0 ? rsqrtf((float)d) : 0.0f;
    } else if (t < 200000) {
        int i = t - 175000; int d = wi[O_TASRC + i];
        wf[O_CTAS + i] = d > 0 ? rsqrtf((float)d) : 0.0f;
    }
}

// ---------- 3-kernel exclusive scan over degc[125000] ----------
__global__ void scan1_kernel(const int* __restrict__ degc, int* __restrict__ bsum) {
    __shared__ int s[256];
    int tid = threadIdx.x;
    int g = blockIdx.x * 256 + tid;
    s[tid] = (g < NSEG) ? degc[g] : 0;
    __syncthreads();
    for (int off = 128; off; off >>= 1) {
        if (tid < off) s[tid] += s[tid + off];
        __syncthreads();
    }
    if (tid == 0) bsum[blockIdx.x] = s[0];
}

__global__ void scan2_kernel(int* __restrict__ bsum, int nb) {
    __shared__ int s[512];
    int t = threadIdx.x;
    int v = (t < nb) ? bsum[t] : 0;
    s[t] = v;
    __syncthreads();
    for (int off = 1; off < 512; off <<= 1) {
        int x = (t >= off) ? s[t - off] : 0;
        __syncthreads();
        s[t] += x;
        __syncthreads();
    }
    if (t < nb) bsum[t] = s[t] - v;   // exclusive
}

__global__ void scan3_kernel(const int* __restrict__ degc, const int* __restrict__ bsum,
                             int* __restrict__ ro, int* __restrict__ cur) {
    __shared__ int s[256];
    int tid = threadIdx.x;
    int g = blockIdx.x * 256 + tid;
    int v = (g < NSEG) ? degc[g] : 0;
    s[tid] = v;
    __syncthreads();
    for (int off = 1; off < 256; off <<= 1) {
        int x = (tid >= off) ? s[tid - off] : 0;
        __syncthreads();
        s[tid] += x;
        __syncthreads();
    }
    int excl = s[tid] - v + bsum[blockIdx.x];
    if (g < NSEG) { ro[g] = excl; cur[g] = excl; }
    if (g == 0) ro[NSEG] = TOTAL_E;
}

// ---------- CSR fill: pos = cursor[dst_row]++, store src + src coefficient ----------
__global__ void fill_kernel(const int* __restrict__ src, const int* __restrict__ dst,
                            const float* __restrict__ cs, int* __restrict__ cur,
                            int* __restrict__ csr_s, float* __restrict__ csr_w,
                            int rowbase, int E) {
    int t = blockIdx.x * blockDim.x + threadIdx.x;
    if (t >= E) return;
    int s = src[t], d = dst[t];
    int pos = atomicAdd(&cur[rowbase + d], 1);
    csr_s[pos] = s;
    csr_w[pos] = cs[s];
}

// ---------- fuse conv2 weights with output projection: U_* = W2_* @ Wp_* ----------
__global__ void fuse_kernel(const float* __restrict__ W2_aa, const float* __restrict__ W2_ta,
                            const float* __restrict__ W2_at, const float* __restrict__ b2_aa,
                            const float* __restrict__ b2_ta, const float* __restrict__ b2_at,
                            const float* __restrict__ Wp_a, const float* __restrict__ bp_a,
                            const float* __restrict__ Wp_t, const float* __restrict__ bp_t,
                            float* __restrict__ U) {
    int t = threadIdx.x;  // 512-thread single block
    if (t < 128) {
        int k = t >> 1, j = t & 1;
        float a = 0.f;
        for (int f = 0; f < 64; ++f) a = fmaf(W2_aa[k * 64 + f], Wp_a[f * 2 + j], a);
        U[t] = a;
    } else if (t < 256) {
        int u = t - 128; int k = u >> 1, j = u & 1;
        float a = 0.f;
        for (int f = 0; f < 64; ++f) a = fmaf(W2_ta[k * 64 + f], Wp_a[f * 2 + j], a);
        U[128 + u] = a;
    } else if (t < 384) {
        int u = t - 256; int k = u >> 1, j = u & 1;
        float a = 0.f;
        for (int f = 0; f < 64; ++f) a = fmaf(W2_at[k * 64 + f], Wp_t[f * 2 + j], a);
        U[256 + u] = a;
    } else if (t < 386) {
        int j = t - 384;
        float a = bp_a[j];
        for (int f = 0; f < 64; ++f) a = fmaf(b2_aa[f] + b2_ta[f], Wp_a[f * 2 + j], a);
        U[384 + j] = a;
    } else if (t < 388) {
        int j = t - 386;
        float a = bp_t[j];
        for (int f = 0; f < 64; ++f) a = fmaf(b2_at[f], Wp_t[f * 2 + j], a);
        U[386 + j] = a;
    }
}

// ---------- conv1 agents: gather(aa)+gather(ta) -> @W1 -> relu -> reduce with U -> p,q ----------
// one wave per node; 4 nodes per 256-thread block; NA = 12500 * 4 exactly.
__global__ void __launch_bounds__(256)
conv1_agents_kernel(const float* __restrict__ x_a, const float* __restrict__ x_t,
                    const int* __restrict__ ro, const int* __restrict__ csr_s,
                    const float* __restrict__ csr_w, const float* __restrict__ c_aa,
                    const float* __restrict__ c_ta_d,
                    const float* __restrict__ W_aa, const float* __restrict__ b_aa,
                    const float* __restrict__ W_ta, const float* __restrict__ b_ta,
                    const float* __restrict__ U,
                    float* __restrict__ p, float* __restrict__ q) {
    __shared__ float sWa[32 * 64];
    __shared__ float sWt[32 * 64];
    __shared__ float sAgg[4][2][32];
    for (int i = threadIdx.x; i < 2048; i += 256) {
        sWa[i] = W_aa[i];
        sWt[i] = W_ta[i];
    }
    int lane = threadIdx.x & 63;
    int wave = threadIdx.x >> 6;
    int k = lane & 31, half = lane >> 5;
    int i = blockIdx.x * 4 + wave;

    float ci = c_aa[i];
    // aa gather (rows ro[i]..ro[i+1]); self-loop folded as extra x_a[i]*ci term
    float accA = 0.f;
    int e0 = ro[i + 1];
    for (int j = ro[i] + half; j < e0; j += 2)
        accA += x_a[csr_s[j] * 32 + k] * csr_w[j];
    if (half == 0) accA += x_a[i * 32 + k] * ci;
    accA += __shfl_xor(accA, 32, 64);
    // ta gather (rows ro[NA+i]..ro[NA+i+1])
    float accT = 0.f;
    int e1 = ro[NA + i + 1];
    for (int j = ro[NA + i] + half; j < e1; j += 2)
        accT += x_t[csr_s[j] * 32 + k] * csr_w[j];
    accT += __shfl_xor(accT, 32, 64);
    if (half == 0) {
        sAgg[wave][0][k] = accA * ci;
        sAgg[wave][1][k] = accT * c_ta_d[i];
    }
    __syncthreads();
    // matvec: h[lane] = relu(bias + agg_aa @ W_aa[:,lane] + agg_ta @ W_ta[:,lane])
    float h = b_aa[lane] + b_ta[lane];
#pragma unroll
    for (int kk = 0; kk < 32; ++kk) {
        h = fmaf(sAgg[wave][0][kk], sWa[kk * 64 + lane], h);
        h = fmaf(sAgg[wave][1][kk], sWt[kk * 64 + lane], h);
    }
    h = fmaxf(h, 0.f);
    // reduce h against U_aa (->p) and U_at (->q)
    float p0 = h * U[lane * 2], p1 = h * U[lane * 2 + 1];
    float q0 = h * U[256 + lane * 2], q1 = h * U[256 + lane * 2 + 1];
    for (int m = 32; m; m >>= 1) {
        p0 += __shfl_xor(p0, m, 64);
        p1 += __shfl_xor(p1, m, 64);
        q0 += __shfl_xor(q0, m, 64);
        q1 += __shfl_xor(q1, m, 64);
    }
    if (lane == 0) {
        p[i * 2] = p0; p[i * 2 + 1] = p1;
        q[i * 2] = q0; q[i * 2 + 1] = q1;
    }
}

// ---------- conv1 targets: gather(at) -> @W1_at -> relu -> reduce with U_ta -> r ----------
__global__ void __launch_bounds__(256)
conv1_targets_kernel(const float* __restrict__ x_a, const int* __restrict__ ro,
                     const int* __restrict__ csr_s, const float* __restrict__ csr_w,
                     const float* __restrict__ c_at_d,
                     const float* __restrict__ W_at, const float* __restrict__ b_at,
                     const float* __restrict__ U, float* __restrict__ r) {
    __shared__ float sW[32 * 64];
    __shared__ float sAgg[4][32];
    for (int i = threadIdx.x; i < 2048; i += 256) sW[i] = W_at[i];
    int lane = threadIdx.x & 63;
    int wave = threadIdx.x >> 6;
    int k = lane & 31, half = lane >> 5;
    int i = blockIdx.x * 4 + wave;

    float acc = 0.f;
    int e0 = ro[2 * NA + i + 1];
    for (int j = ro[2 * NA + i] + half; j < e0; j += 2)
        acc += x_a[csr_s[j] * 32 + k] * csr_w[j];
    acc += __shfl_xor(acc, 32, 64);
    if (half == 0) sAgg[wave][k] = acc * c_at_d[i];
    __syncthreads();
    float h = b_at[lane];
#pragma unroll
    for (int kk = 0; kk < 32; ++kk) h = fmaf(sAgg[wave][kk], sW[kk * 64 + lane], h);
    h = fmaxf(h, 0.f);
    float r0 = h * U[128 + lane * 2], r1 = h * U[128 + lane * 2 + 1];
    for (int m = 32; m; m >>= 1) {
        r0 += __shfl_xor(r0, m, 64);
        r1 += __shfl_xor(r1, m, 64);
    }
    if (lane == 0) { r[i * 2] = r0; r[i * 2 + 1] = r1; }
}

// ---------- conv2+proj for agents: gather p (aa) and r (ta) into out ----------
__global__ void out_agents_kernel(const float* __restrict__ p, const float* __restrict__ r,
                                  const int* __restrict__ ro, const int* __restrict__ csr_s,
                                  const float* __restrict__ csr_w, const float* __restrict__ c_aa,
                                  const float* __restrict__ c_ta_d, const float* __restrict__ U,
                                  float* __restrict__ out) {
    int t = blockIdx.x * blockDim.x + threadIdx.x;
    if (t >= NA * 2) return;
    int i = t >> 1, j = t & 1;
    float ci = c_aa[i];
    float acc = ci * p[i * 2 + j];          // self-loop: becomes ci^2 * p after scale
    int e0 = ro[i + 1];
    for (int jj = ro[i]; jj < e0; ++jj)
        acc += p[csr_s[jj] * 2 + j] * csr_w[jj];
    acc *= ci;
    float acc2 = 0.f;
    int e1 = ro[NA + i + 1];
    for (int jj = ro[NA + i]; jj < e1; ++jj)
        acc2 += r[csr_s[jj] * 2 + j] * csr_w[jj];
    out[t] = U[384 + j] + acc + acc2 * c_ta_d[i];
}

// ---------- conv2+proj for targets: gather q (at) into out ----------
__global__ void out_targets_kernel(const float* __restrict__ q, const int* __restrict__ ro,
                                   const int* __restrict__ csr_s, const float* __restrict__ csr_w,
                                   const float* __restrict__ c_at_d, const float* __restrict__ U,
                                   float* __restrict__ out) {
    int t = blockIdx.x * blockDim.x + threadIdx.x;
    if (t >= NT * 2) return;
    int i = t >> 1, j = t & 1;
    float acc = 0.f;
    int e0 = ro[2 * NA + i + 1];
    for (int jj = ro[2 * NA + i]; jj < e0; ++jj)
        acc += q[csr_s[jj] * 2 + j] * csr_w[jj];
    out[NA * 2 + t] = U[386 + j] + acc * c_at_d[i];
}

extern "C" void kernel_launch(void* const* d_in, const int* in_sizes, int n_in,
                              void* d_out, int out_size, void* d_ws, size_t ws_size,
                              hipStream_t stream) {
    const float* x_a   = (const float*)d_in[1];
    const float* x_t   = (const float*)d_in[2];
    const int* src_aa  = (const int*)d_in[3];
    const int* dst_aa  = (const int*)d_in[4];
    const int* src_at  = (const int*)d_in[5];
    const int* dst_at  = (const int*)d_in[6];
    const int* src_ta  = (const int*)d_in[7];
    const int* dst_ta  = (const int*)d_in[8];
    const float* W1_aa = (const float*)d_in[9];
    const float* b1_aa = (const float*)d_in[10];
    const float* W1_at = (const float*)d_in[11];
    const float* b1_at = (const float*)d_in[12];
    const float* W1_ta = (const float*)d_in[13];
    const float* b1_ta = (const float*)d_in[14];
    const float* W2_aa = (const float*)d_in[15];
    const float* b2_aa = (const float*)d_in[16];
    const float* W2_at = (const float*)d_in[17];
    const float* b2_at = (const float*)d_in[18];
    const float* W2_ta = (const float*)d_in[19];
    const float* b2_ta = (const float*)d_in[20];
    const float* Wp_a  = (const float*)d_in[21];
    const float* bp_a  = (const float*)d_in[22];
    const float* Wp_t  = (const float*)d_in[23];
    const float* bp_t  = (const float*)d_in[24];

    int*   wi  = (int*)d_ws;
    float* wf  = (float*)d_ws;
    float* out = (float*)d_out;

    const int B = 256;
    auto blk = [](int n) { return (n + 255) / 256; };
    const int NB_SCAN = (NSEG + 255) / 256;   // 489

    // zero the degree histograms
    hipMemsetAsync(wi, 0, (size_t)O_ZEND * 4, stream);

    // degrees (int histograms)
    deg1_kernel<<<blk(EAA), B, 0, stream>>>(dst_aa, wi + O_DEGC, EAA);
    deg2_kernel<<<blk(ETA), B, 0, stream>>>(src_ta, dst_ta, wi + O_TASRC, wi + O_DEGC + NA, ETA);
    deg2_kernel<<<blk(EAT), B, 0, stream>>>(src_at, dst_at, wi + O_ATSRC, wi + O_DEGC + 2 * NA, EAT);

    // coefficients
    coef_kernel<<<blk(200000), B, 0, stream>>>(wi, wf);

    // CSR row offsets (exclusive scan over concatenated degrees)
    scan1_kernel<<<NB_SCAN, 256, 0, stream>>>(wi + O_DEGC, wi + O_BSUM);
    scan2_kernel<<<1, 512, 0, stream>>>(wi + O_BSUM, NB_SCAN);
    scan3_kernel<<<NB_SCAN, 256, 0, stream>>>(wi + O_DEGC, wi + O_BSUM, wi + O_RO, wi + O_CUR);

    // CSR fill (src index + src-side coefficient)
    fill_kernel<<<blk(EAA), B, 0, stream>>>(src_aa, dst_aa, wf + O_CAA, wi + O_CUR,
                                            wi + O_CSRS, wf + O_CSRW, 0, EAA);
    fill_kernel<<<blk(ETA), B, 0, stream>>>(src_ta, dst_ta, wf + O_CTAS, wi + O_CUR,
                                            wi + O_CSRS, wf + O_CSRW, NA, ETA);
    fill_kernel<<<blk(EAT), B, 0, stream>>>(src_at, dst_at, wf + O_CATS, wi + O_CUR,
                                            wi + O_CSRS, wf + O_CSRW, 2 * NA, EAT);

    // fuse conv2 weights with output projection
    fuse_kernel<<<1, 512, 0, stream>>>(W2_aa, W2_ta, W2_at, b2_aa, b2_ta, b2_at,
                                       Wp_a, bp_a, Wp_t, bp_t, wf + O_U);

    // conv1 (gather + transform + relu + U-reduction), writes p,q,r only
    conv1_agents_kernel<<<NA / 4, 256, 0, stream>>>(
        x_a, x_t, wi + O_RO, wi + O_CSRS, wf + O_CSRW, wf + O_CAA, wf + O_CTAD,
        W1_aa, b1_aa, W1_ta, b1_ta, wf + O_U, wf + O_P, wf + O_Q);
    conv1_targets_kernel<<<NT / 4, 256, 0, stream>>>(
        x_a, wi + O_RO, wi + O_CSRS, wf + O_CSRW, wf + O_CATD,
        W1_at, b1_at, wf + O_U, wf + O_R);

    // conv2 + projection via gather, direct to output
    out_agents_kernel<<<blk(NA * 2), B, 0, stream>>>(
        wf + O_P, wf + O_R, wi + O_RO, wi + O_CSRS, wf + O_CSRW,
        wf + O_CAA, wf + O_CTAD, wf + O_U, out);
    out_targets_kernel<<<blk(NT * 2), B, 0, stream>>>(
        wf + O_Q, wi + O_RO, wi + O_CSRS, wf + O_CSRW,
        wf + O_CATD, wf + O_U, out);
}

// Round 3
// 433.710 us; speedup vs baseline: 2.5382x; 1.1151x over previous
//
#include <hip/hip_runtime.h>

#define NA 50000
#define NT 25000
#define EAA 800000
#define EAT 400000
#define ETA 400000
#define NSEG 125000          // NA + NA + NT rows: [aa | ta | at]
#define TOTAL_E 1600000

// ---- workspace layout (4-byte element offsets) ----
#define O_DEGC    0          // int[125008]: concat degrees  aa-dst[NA] | ta-dst[NA] | at-dst[NT]
#define O_ATSRC   125008     // int[50000]: at-relation src out-degree (over NA)
#define O_TASRC   175008     // int[25000]: ta-relation src out-degree (over NT)
#define O_ZEND    200032     // memset 0 .. here
#define O_RO      200032     // int[125008]: CSR row offsets (global into edge buffer)
#define O_CUR     325040     // int[125000]: fill cursors
#define O_BSUM    450040     // int[512]: scan block sums
#define O_CAA     450552     // float[50000]: rsqrt(indeg_aa+1)
#define O_CTAD    500552     // float[50000]: ta dst coef (over NA)
#define O_CATD    550552     // float[25000]: at dst coef (over NT)
#define O_CATS    575552     // float[50000]: at src coef (over NA)
#define O_CTAS    625552     // float[25000]: ta src coef (over NT)
#define O_U       650552     // float[512]: U_aa[128] | U_ta[128] | U_at[128] | v[4]
#define O_P       651064     // float[100000]: p = h_a @ U_aa
#define O_Q       751064     // float[100000]: q = h_a @ U_at
#define O_R       851064     // float[50000]:  r = h_t @ U_ta
#define O_CSR     901064     // int2[1600000]: packed {src, bitcast(weight)}  (8B aligned: offset even)
// total 901064 + 3200000 = 4,101,064 elems = 16.4 MB

// ---------- fused degree counting over all 3 relations ----------
__global__ void deg_all_kernel(const int* __restrict__ dst_aa,
                               const int* __restrict__ src_ta, const int* __restrict__ dst_ta,
                               const int* __restrict__ src_at, const int* __restrict__ dst_at,
                               int* __restrict__ wi) {
    int t = blockIdx.x * blockDim.x + threadIdx.x;
    if (t < EAA) {
        atomicAdd(&wi[O_DEGC + dst_aa[t]], 1);
    } else if (t < EAA + ETA) {
        int u = t - EAA;
        atomicAdd(&wi[O_DEGC + NA + dst_ta[u]], 1);
        atomicAdd(&wi[O_TASRC + src_ta[u]], 1);
    } else if (t < TOTAL_E) {
        int u = t - EAA - ETA;
        atomicAdd(&wi[O_DEGC + 2 * NA + dst_at[u]], 1);
        atomicAdd(&wi[O_ATSRC + src_at[u]], 1);
    }
}

// ---------- degrees -> normalization coefficients ----------
__global__ void coef_kernel(const int* __restrict__ wi, float* __restrict__ wf) {
    int t = blockIdx.x * blockDim.x + threadIdx.x;
    if (t < 50000) {
        wf[O_CAA + t] = rsqrtf((float)wi[O_DEGC + t] + 1.0f);
    } else if (t < 100000) {
        int i = t - 50000; int d = wi[O_DEGC + NA + i];
        wf[O_CTAD + i] = d > 0 ? rsqrtf((float)d) : 0.0f;
    } else if (t < 125000) {
        int i = t - 100000; int d = wi[O_DEGC + 2 * NA + i];
        wf[O_CATD + i] = d > 0 ? rsqrtf((float)d) : 0.0f;
    } else if (t < 175000) {
        int i = t - 125000; int d = wi[O_ATSRC + i];
        wf[O_CATS + i] = d > 0 ? rsqrtf((float)d) : 0.0f;
    } else if (t < 200000) {
        int i = t - 175000; int d = wi[O_TASRC + i];
        wf[O_CTAS + i] = d > 0 ? rsqrtf((float)d) : 0.0f;
    }
}

// ---------- 3-kernel exclusive scan over degc[125000] ----------
__global__ void scan1_kernel(const int* __restrict__ degc, int* __restrict__ bsum) {
    __shared__ int s[256];
    int tid = threadIdx.x;
    int g = blockIdx.x * 256 + tid;
    s[tid] = (g < NSEG) ? degc[g] : 0;
    __syncthreads();
    for (int off = 128; off; off >>= 1) {
        if (tid < off) s[tid] += s[tid + off];
        __syncthreads();
    }
    if (tid == 0) bsum[blockIdx.x] = s[0];
}

__global__ void scan2_kernel(int* __restrict__ bsum, int nb) {
    __shared__ int s[512];
    int t = threadIdx.x;
    int v = (t < nb) ? bsum[t] : 0;
    s[t] = v;
    __syncthreads();
    for (int off = 1; off < 512; off <<= 1) {
        int x = (t >= off) ? s[t - off] : 0;
        __syncthreads();
        s[t] += x;
        __syncthreads();
    }
    if (t < nb) bsum[t] = s[t] - v;   // exclusive
}

__global__ void scan3_kernel(const int* __restrict__ degc, const int* __restrict__ bsum,
                             int* __restrict__ ro, int* __restrict__ cur) {
    __shared__ int s[256];
    int tid = threadIdx.x;
    int g = blockIdx.x * 256 + tid;
    int v = (g < NSEG) ? degc[g] : 0;
    s[tid] = v;
    __syncthreads();
    for (int off = 1; off < 256; off <<= 1) {
        int x = (tid >= off) ? s[tid - off] : 0;
        __syncthreads();
        s[tid] += x;
        __syncthreads();
    }
    int excl = s[tid] - v + bsum[blockIdx.x];
    if (g < NSEG) { ro[g] = excl; cur[g] = excl; }
    if (g == 0) ro[NSEG] = TOTAL_E;
}

// ---------- fused CSR fill: pos = cursor[row]++, one 8B packed store ----------
__global__ void fill_all_kernel(const int* __restrict__ src_aa, const int* __restrict__ dst_aa,
                                const int* __restrict__ src_ta, const int* __restrict__ dst_ta,
                                const int* __restrict__ src_at, const int* __restrict__ dst_at,
                                const float* __restrict__ wf, int* __restrict__ cur,
                                int2* __restrict__ csr) {
    int t = blockIdx.x * blockDim.x + threadIdx.x;
    int s, d, base;
    const float* cs;
    if (t < EAA) {
        s = src_aa[t]; d = dst_aa[t]; base = 0;      cs = wf + O_CAA;
    } else if (t < EAA + ETA) {
        int u = t - EAA;
        s = src_ta[u]; d = dst_ta[u]; base = NA;     cs = wf + O_CTAS;
    } else if (t < TOTAL_E) {
        int u = t - EAA - ETA;
        s = src_at[u]; d = dst_at[u]; base = 2 * NA; cs = wf + O_CATS;
    } else return;
    int pos = atomicAdd(&cur[base + d], 1);
    csr[pos] = make_int2(s, __float_as_int(cs[s]));
}

// ---------- fuse conv2 weights with output projection: U_* = W2_* @ Wp_* ----------
__global__ void fuse_kernel(const float* __restrict__ W2_aa, const float* __restrict__ W2_ta,
                            const float* __restrict__ W2_at, const float* __restrict__ b2_aa,
                            const float* __restrict__ b2_ta, const float* __restrict__ b2_at,
                            const float* __restrict__ Wp_a, const float* __restrict__ bp_a,
                            const float* __restrict__ Wp_t, const float* __restrict__ bp_t,
                            float* __restrict__ U) {
    int t = threadIdx.x;  // 512-thread single block
    if (t < 128) {
        int k = t >> 1, j = t & 1;
        float a = 0.f;
        for (int f = 0; f < 64; ++f) a = fmaf(W2_aa[k * 64 + f], Wp_a[f * 2 + j], a);
        U[t] = a;
    } else if (t < 256) {
        int u = t - 128; int k = u >> 1, j = u & 1;
        float a = 0.f;
        for (int f = 0; f < 64; ++f) a = fmaf(W2_ta[k * 64 + f], Wp_a[f * 2 + j], a);
        U[128 + u] = a;
    } else if (t < 384) {
        int u = t - 256; int k = u >> 1, j = u & 1;
        float a = 0.f;
        for (int f = 0; f < 64; ++f) a = fmaf(W2_at[k * 64 + f], Wp_t[f * 2 + j], a);
        U[256 + u] = a;
    } else if (t < 386) {
        int j = t - 384;
        float a = bp_a[j];
        for (int f = 0; f < 64; ++f) a = fmaf(b2_aa[f] + b2_ta[f], Wp_a[f * 2 + j], a);
        U[384 + j] = a;
    } else if (t < 388) {
        int j = t - 386;
        float a = bp_t[j];
        for (int f = 0; f < 64; ++f) a = fmaf(b2_at[f], Wp_t[f * 2 + j], a);
        U[386 + j] = a;
    }
}

// ---------- conv1 agents: float4 gather (8 edges/wave-iter) -> @W1 -> relu -> U-reduce -> p,q ----------
// one wave per node; 4 nodes per 256-thread block; NA = 12500 * 4 exactly.
__global__ void __launch_bounds__(256)
conv1_agents_kernel(const float* __restrict__ x_a, const float* __restrict__ x_t,
                    const int* __restrict__ ro, const int2* __restrict__ csr,
                    const float* __restrict__ c_aa, const float* __restrict__ c_ta_d,
                    const float* __restrict__ W_aa, const float* __restrict__ b_aa,
                    const float* __restrict__ W_ta, const float* __restrict__ b_ta,
                    const float* __restrict__ U,
                    float* __restrict__ p, float* __restrict__ q) {
    __shared__ float sWa[32 * 64];
    __shared__ float sWt[32 * 64];
    __shared__ float sAgg[4][2][32];
    for (int i = threadIdx.x; i < 2048; i += 256) {
        sWa[i] = W_aa[i];
        sWt[i] = W_ta[i];
    }
    int lane = threadIdx.x & 63;
    int wave = threadIdx.x >> 6;
    int e8 = lane >> 3, k4 = lane & 7;   // edge slot / float4 slice
    int i = blockIdx.x * 4 + wave;
    float ci = c_aa[i];

    // aa gather: 8 edges in parallel, each covered by 8 lanes x float4
    float4 accA = make_float4(0.f, 0.f, 0.f, 0.f);
    int e0 = ro[i + 1];
    for (int j = ro[i] + e8; j < e0; j += 8) {
        int2 ew = csr[j];
        float w = __int_as_float(ew.y);
        float4 xv = *(const float4*)(x_a + (size_t)ew.x * 32 + k4 * 4);
        accA.x = fmaf(xv.x, w, accA.x);
        accA.y = fmaf(xv.y, w, accA.y);
        accA.z = fmaf(xv.z, w, accA.z);
        accA.w = fmaf(xv.w, w, accA.w);
    }
    if (e8 == 0) {  // self-loop term
        float4 xv = *(const float4*)(x_a + (size_t)i * 32 + k4 * 4);
        accA.x = fmaf(xv.x, ci, accA.x);
        accA.y = fmaf(xv.y, ci, accA.y);
        accA.z = fmaf(xv.z, ci, accA.z);
        accA.w = fmaf(xv.w, ci, accA.w);
    }
    // ta gather
    float4 accT = make_float4(0.f, 0.f, 0.f, 0.f);
    int e1 = ro[NA + i + 1];
    for (int j = ro[NA + i] + e8; j < e1; j += 8) {
        int2 ew = csr[j];
        float w = __int_as_float(ew.y);
        float4 xv = *(const float4*)(x_t + (size_t)ew.x * 32 + k4 * 4);
        accT.x = fmaf(xv.x, w, accT.x);
        accT.y = fmaf(xv.y, w, accT.y);
        accT.z = fmaf(xv.z, w, accT.z);
        accT.w = fmaf(xv.w, w, accT.w);
    }
    // reduce over the 8 edge slots
#pragma unroll
    for (int m = 8; m <= 32; m <<= 1) {
        accA.x += __shfl_xor(accA.x, m, 64);
        accA.y += __shfl_xor(accA.y, m, 64);
        accA.z += __shfl_xor(accA.z, m, 64);
        accA.w += __shfl_xor(accA.w, m, 64);
        accT.x += __shfl_xor(accT.x, m, 64);
        accT.y += __shfl_xor(accT.y, m, 64);
        accT.z += __shfl_xor(accT.z, m, 64);
        accT.w += __shfl_xor(accT.w, m, 64);
    }
    if (lane < 8) {
        float cta = c_ta_d[i];
        *(float4*)&sAgg[wave][0][k4 * 4] =
            make_float4(accA.x * ci, accA.y * ci, accA.z * ci, accA.w * ci);
        *(float4*)&sAgg[wave][1][k4 * 4] =
            make_float4(accT.x * cta, accT.y * cta, accT.z * cta, accT.w * cta);
    }
    __syncthreads();
    // matvec: h[lane] = relu(bias + agg_aa @ W_aa[:,lane] + agg_ta @ W_ta[:,lane])
    float h = b_aa[lane] + b_ta[lane];
#pragma unroll
    for (int kk = 0; kk < 32; ++kk) {
        h = fmaf(sAgg[wave][0][kk], sWa[kk * 64 + lane], h);
        h = fmaf(sAgg[wave][1][kk], sWt[kk * 64 + lane], h);
    }
    h = fmaxf(h, 0.f);
    // reduce h against U_aa (->p) and U_at (->q)
    float p0 = h * U[lane * 2], p1 = h * U[lane * 2 + 1];
    float q0 = h * U[256 + lane * 2], q1 = h * U[256 + lane * 2 + 1];
#pragma unroll
    for (int m = 32; m; m >>= 1) {
        p0 += __shfl_xor(p0, m, 64);
        p1 += __shfl_xor(p1, m, 64);
        q0 += __shfl_xor(q0, m, 64);
        q1 += __shfl_xor(q1, m, 64);
    }
    if (lane == 0) {
        *(float2*)&p[i * 2] = make_float2(p0, p1);
        *(float2*)&q[i * 2] = make_float2(q0, q1);
    }
}

// ---------- conv1 targets: float4 gather(at) -> @W1_at -> relu -> U_ta-reduce -> r ----------
__global__ void __launch_bounds__(256)
conv1_targets_kernel(const float* __restrict__ x_a, const int* __restrict__ ro,
                     const int2* __restrict__ csr, const float* __restrict__ c_at_d,
                     const float* __restrict__ W_at, const float* __restrict__ b_at,
                     const float* __restrict__ U, float* __restrict__ r) {
    __shared__ float sW[32 * 64];
    __shared__ float sAgg[4][32];
    for (int i = threadIdx.x; i < 2048; i += 256) sW[i] = W_at[i];
    int lane = threadIdx.x & 63;
    int wave = threadIdx.x >> 6;
    int e8 = lane >> 3, k4 = lane & 7;
    int i = blockIdx.x * 4 + wave;

    float4 acc = make_float4(0.f, 0.f, 0.f, 0.f);
    int e0 = ro[2 * NA + i + 1];
    for (int j = ro[2 * NA + i] + e8; j < e0; j += 8) {
        int2 ew = csr[j];
        float w = __int_as_float(ew.y);
        float4 xv = *(const float4*)(x_a + (size_t)ew.x * 32 + k4 * 4);
        acc.x = fmaf(xv.x, w, acc.x);
        acc.y = fmaf(xv.y, w, acc.y);
        acc.z = fmaf(xv.z, w, acc.z);
        acc.w = fmaf(xv.w, w, acc.w);
    }
#pragma unroll
    for (int m = 8; m <= 32; m <<= 1) {
        acc.x += __shfl_xor(acc.x, m, 64);
        acc.y += __shfl_xor(acc.y, m, 64);
        acc.z += __shfl_xor(acc.z, m, 64);
        acc.w += __shfl_xor(acc.w, m, 64);
    }
    if (lane < 8) {
        float cd = c_at_d[i];
        *(float4*)&sAgg[wave][k4 * 4] =
            make_float4(acc.x * cd, acc.y * cd, acc.z * cd, acc.w * cd);
    }
    __syncthreads();
    float h = b_at[lane];
#pragma unroll
    for (int kk = 0; kk < 32; ++kk) h = fmaf(sAgg[wave][kk], sW[kk * 64 + lane], h);
    h = fmaxf(h, 0.f);
    float r0 = h * U[128 + lane * 2], r1 = h * U[128 + lane * 2 + 1];
#pragma unroll
    for (int m = 32; m; m >>= 1) {
        r0 += __shfl_xor(r0, m, 64);
        r1 += __shfl_xor(r1, m, 64);
    }
    if (lane == 0) *(float2*)&r[i * 2] = make_float2(r0, r1);
}

// ---------- conv2+proj agents: 8 threads/node (4 edge slots x 2 comps) ----------
__global__ void __launch_bounds__(256)
out_agents_kernel(const float* __restrict__ p, const float* __restrict__ r,
                  const int* __restrict__ ro, const int2* __restrict__ csr,
                  const float* __restrict__ c_aa, const float* __restrict__ c_ta_d,
                  const float* __restrict__ U, float* __restrict__ out) {
    int t = blockIdx.x * blockDim.x + threadIdx.x;
    if (t >= NA * 8) return;
    int i = t >> 3, sub = t & 7, slot = sub >> 1, j = sub & 1;
    float ci = c_aa[i];
    float accA = (slot == 0) ? ci * p[i * 2 + j] : 0.f;   // self-loop
    int e0 = ro[i + 1];
    for (int jj = ro[i] + slot; jj < e0; jj += 4) {
        int2 ew = csr[jj];
        accA = fmaf(p[ew.x * 2 + j], __int_as_float(ew.y), accA);
    }
    float accT = 0.f;
    int e1 = ro[NA + i + 1];
    for (int jj = ro[NA + i] + slot; jj < e1; jj += 4) {
        int2 ew = csr[jj];
        accT = fmaf(r[ew.x * 2 + j], __int_as_float(ew.y), accT);
    }
    accA += __shfl_xor(accA, 2, 64);
    accA += __shfl_xor(accA, 4, 64);
    accT += __shfl_xor(accT, 2, 64);
    accT += __shfl_xor(accT, 4, 64);
    if (slot == 0)
        out[i * 2 + j] = U[384 + j] + accA * ci + accT * c_ta_d[i];
}

// ---------- conv2+proj targets ----------
__global__ void __launch_bounds__(256)
out_targets_kernel(const float* __restrict__ q, const int* __restrict__ ro,
                   const int2* __restrict__ csr, const float* __restrict__ c_at_d,
                   const float* __restrict__ U, float* __restrict__ out) {
    int t = blockIdx.x * blockDim.x + threadIdx.x;
    if (t >= NT * 8) return;
    int i = t >> 3, sub = t & 7, slot = sub >> 1, j = sub & 1;
    float acc = 0.f;
    int e0 = ro[2 * NA + i + 1];
    for (int jj = ro[2 * NA + i] + slot; jj < e0; jj += 4) {
        int2 ew = csr[jj];
        acc = fmaf(q[ew.x * 2 + j], __int_as_float(ew.y), acc);
    }
    acc += __shfl_xor(acc, 2, 64);
    acc += __shfl_xor(acc, 4, 64);
    if (slot == 0)
        out[NA * 2 + i * 2 + j] = U[386 + j] + acc * c_at_d[i];
}

extern "C" void kernel_launch(void* const* d_in, const int* in_sizes, int n_in,
                              void* d_out, int out_size, void* d_ws, size_t ws_size,
                              hipStream_t stream) {
    const float* x_a   = (const float*)d_in[1];
    const float* x_t   = (const float*)d_in[2];
    const int* src_aa  = (const int*)d_in[3];
    const int* dst_aa  = (const int*)d_in[4];
    const int* src_at  = (const int*)d_in[5];
    const int* dst_at  = (const int*)d_in[6];
    const int* src_ta  = (const int*)d_in[7];
    const int* dst_ta  = (const int*)d_in[8];
    const float* W1_aa = (const float*)d_in[9];
    const float* b1_aa = (const float*)d_in[10];
    const float* W1_at = (const float*)d_in[11];
    const float* b1_at = (const float*)d_in[12];
    const float* W1_ta = (const float*)d_in[13];
    const float* b1_ta = (const float*)d_in[14];
    const float* W2_aa = (const float*)d_in[15];
    const float* b2_aa = (const float*)d_in[16];
    const float* W2_at = (const float*)d_in[17];
    const float* b2_at = (const float*)d_in[18];
    const float* W2_ta = (const float*)d_in[19];
    const float* b2_ta = (const float*)d_in[20];
    const float* Wp_a  = (const float*)d_in[21];
    const float* bp_a  = (const float*)d_in[22];
    const float* Wp_t  = (const float*)d_in[23];
    const float* bp_t  = (const float*)d_in[24];

    int*   wi  = (int*)d_ws;
    float* wf  = (float*)d_ws;
    int2*  csr = (int2*)((int*)d_ws + O_CSR);
    float* out = (float*)d_out;

    const int B = 256;
    auto blk = [](int n) { return (n + 255) / 256; };
    const int NB_SCAN = (NSEG + 255) / 256;   // 489

    // zero the degree histograms
    hipMemsetAsync(wi, 0, (size_t)O_ZEND * 4, stream);

    // degrees (fused, int histograms)
    deg_all_kernel<<<blk(TOTAL_E), B, 0, stream>>>(dst_aa, src_ta, dst_ta, src_at, dst_at, wi);

    // coefficients
    coef_kernel<<<blk(200000), B, 0, stream>>>(wi, wf);

    // CSR row offsets (exclusive scan over concatenated degrees)
    scan1_kernel<<<NB_SCAN, 256, 0, stream>>>(wi + O_DEGC, wi + O_BSUM);
    scan2_kernel<<<1, 512, 0, stream>>>(wi + O_BSUM, NB_SCAN);
    scan3_kernel<<<NB_SCAN, 256, 0, stream>>>(wi + O_DEGC, wi + O_BSUM, wi + O_RO, wi + O_CUR);

    // fused CSR fill (packed {src, weight} 8B store)
    fill_all_kernel<<<blk(TOTAL_E), B, 0, stream>>>(src_aa, dst_aa, src_ta, dst_ta,
                                                    src_at, dst_at, wf, wi + O_CUR, csr);

    // fuse conv2 weights with output projection
    fuse_kernel<<<1, 512, 0, stream>>>(W2_aa, W2_ta, W2_at, b2_aa, b2_ta, b2_at,
                                       Wp_a, bp_a, Wp_t, bp_t, wf + O_U);

    // conv1 (float4 gather + transform + relu + U-reduction), writes p,q,r only
    conv1_agents_kernel<<<NA / 4, 256, 0, stream>>>(
        x_a, x_t, wi + O_RO, csr, wf + O_CAA, wf + O_CTAD,
        W1_aa, b1_aa, W1_ta, b1_ta, wf + O_U, wf + O_P, wf + O_Q);
    conv1_targets_kernel<<<NT / 4, 256, 0, stream>>>(
        x_a, wi + O_RO, csr, wf + O_CATD, W1_at, b1_at, wf + O_U, wf + O_R);

    // conv2 + projection via gather, direct to output
    out_agents_kernel<<<blk(NA * 8), B, 0, stream>>>(
        wf + O_P, wf + O_R, wi + O_RO, csr, wf + O_CAA, wf + O_CTAD, wf + O_U, out);
    out_targets_kernel<<<blk(NT * 8), B, 0, stream>>>(
        wf + O_Q, wi + O_RO, csr, wf + O_CATD, wf + O_U, out);
}